// Round 2
// baseline (27.652 us; speedup 1.0000x reference)
//
#include <hip/hip_runtime.h>
#include <math.h>

#define DT    0.019999999552965164f
#define GRAV  9.8100004196167f
#define GEAR  100.0f

__global__ __launch_bounds__(256) void cartpole_rk4_kernel(
    const float* __restrict__ x,
    const float* __restrict__ v,
    const float* __restrict__ th,
    const float* __restrict__ om,
    const float* __restrict__ u,
    const float* __restrict__ pI,
    const float* __restrict__ pb,
    const float* __restrict__ pd,
    const float* __restrict__ pl,
    const float* __restrict__ pm1,
    const float* __restrict__ pm2,
    float4* __restrict__ out,
    int n)
{
    int i = blockIdx.x * blockDim.x + threadIdx.x;
    if (i >= n) return;

    // uniform physical parameters
    const float I  = pI[0];
    const float b  = pb[0];
    const float d  = pd[0];
    const float l  = pl[0];
    const float m1 = pm1[0];
    const float m2 = pm2[0];

    const float M     = m1 + m2;
    const float m2l   = m2 * l;
    const float Ieff  = I + m2l * l;        // I + m2*l*l
    const float m2gl  = m2l * GRAV;         // m2*g*l
    const float IeffM = Ieff * M;

    const float x0 = x[i];
    const float v0 = v[i];
    const float t0 = th[i];
    const float o0 = om[i];
    const float F  = GEAR * u[i];

    // deriv of (v, omega) given state (v_, th_, om_); x-deriv is v_, th-deriv is om_
    auto deriv = [&](float v_, float t_, float o_, float& xdd, float& tdd) {
        float s, c;
        __sincosf(t_, &s, &c);
        float A    = F - b * v_ + m2l * o_ * o_ * s;
        float Bq   = m2gl * s - d * o_;
        float mlc  = m2l * c;
        float D    = IeffM - mlc * mlc;
        float invD = __builtin_amdgcn_rcpf(D);
        xdd = (Ieff * A - mlc * Bq) * invD;
        tdd = (M * Bq - mlc * A) * invD;
    };

    const float half = 0.5f * DT;

    // k1
    float k1v, k1o;
    deriv(v0, t0, o0, k1v, k1o);
    // k1x = v0, k1t = o0

    // state for k2
    float v2 = v0 + half * k1v;
    float t2 = t0 + half * o0;
    float o2 = o0 + half * k1o;
    float k2v, k2o;
    deriv(v2, t2, o2, k2v, k2o);
    // k2x = v2, k2t = o2

    // state for k3
    float v3 = v0 + half * k2v;
    float t3 = t0 + half * o2;
    float o3 = o0 + half * k2o;
    float k3v, k3o;
    deriv(v3, t3, o3, k3v, k3o);
    // k3x = v3, k3t = o3

    // state for k4
    float v4 = v0 + DT * k3v;
    float t4 = t0 + DT * o3;
    float o4 = o0 + DT * k3o;
    float k4v, k4o;
    deriv(v4, t4, o4, k4v, k4o);
    // k4x = v4, k4t = o4

    const float w = DT * (1.0f / 6.0f);

    float xn = x0 + w * (v0  + 2.0f * v2  + 2.0f * v3  + v4);
    float vn = v0 + w * (k1v + 2.0f * k2v + 2.0f * k3v + k4v);
    float tn = t0 + w * (o0  + 2.0f * o2  + 2.0f * o3  + o4);
    float on = o0 + w * (k1o + 2.0f * k2o + 2.0f * k3o + k4o);

    out[i] = make_float4(xn, vn, tn, on);
}

extern "C" void kernel_launch(void* const* d_in, const int* in_sizes, int n_in,
                              void* d_out, int out_size, void* d_ws, size_t ws_size,
                              hipStream_t stream) {
    const float* x   = (const float*)d_in[0];
    const float* v   = (const float*)d_in[1];
    const float* th  = (const float*)d_in[2];
    const float* om  = (const float*)d_in[3];
    const float* u   = (const float*)d_in[4];
    const float* pI  = (const float*)d_in[5];
    const float* pb  = (const float*)d_in[6];
    const float* pd  = (const float*)d_in[7];
    const float* pl  = (const float*)d_in[8];
    const float* pm1 = (const float*)d_in[9];
    const float* pm2 = (const float*)d_in[10];

    int n = in_sizes[0];  // B = 4194304
    float4* out = (float4*)d_out;

    int block = 256;
    int grid = (n + block - 1) / block;
    cartpole_rk4_kernel<<<grid, block, 0, stream>>>(
        x, v, th, om, u, pI, pb, pd, pl, pm1, pm2, out, n);
}